// Round 10
// baseline (274.336 us; speedup 1.0000x reference)
//
#include <hip/hip_runtime.h>

#define BB 4
#define CC 64
#define HH 128
#define WW 128
#define NN 16

__device__ __forceinline__ float softplus_f(float x) {
    float e = __expf(-fabsf(x));
    return fmaxf(x, 0.0f) + __logf(1.0f + e);
}

// ---------------------------------------------------------------------------
// Horizontal scan. grid=256, block=128. Block = 2 rows (b,h0/h0+1) x 64 ch.
// All f32 (model proven R0-R9: ref dtypes/shapes are literal; C=64).
// ---------------------------------------------------------------------------
__global__ __launch_bounds__(128) void k_h(
    const float* __restrict__ x, const float* __restrict__ xpw,
    const float* __restrict__ A_log, const float* __restrict__ Dv,
    const float* __restrict__ dtw, const float* __restrict__ dtb,
    float* __restrict__ out)
{
    __shared__ float sh[4224];     // xt[64][65] (4160) aliased with ytile[128][33]
    __shared__ float pr[64 * 37];  // [pix][37] proj (pad 37 -> stride-5 banks)

    const int t = threadIdx.x;     // 0..127
    const int b = blockIdx.x >> 6; // 4 b * 64 h-pairs
    const int h0 = (blockIdx.x & 63) * 2;

    const int s_sc = t >> 6;       // row within pair (0/1), wave-uniform
    const int d = t & 63;          // channel
    const int pix = t & 63;        // proj pixel
    const int pg = t >> 6;         // proj half: 18 outputs each

    float A[NN], hs[NN];
    for (int n = 0; n < NN; ++n) A[n] = -__expf(A_log[d * NN + n]);
    for (int n = 0; n < NN; ++n) hs[n] = 0.f;
    const float w40 = dtw[d * 4 + 0], w41 = dtw[d * 4 + 1];
    const float w42 = dtw[d * 4 + 2], w43 = dtw[d * 4 + 3];
    const float bias = dtb[d], Dd = Dv[d];

    for (int w0 = 0; w0 < WW; w0 += 32) {
        // ---- L: stage xt[c][s*32+wi], coalesced 128B rows ----
        for (int pass = 0; pass < 32; ++pass) {
            int idx = pass * 128 + t;
            int wi = idx & 31, s = (idx >> 5) & 1, c = idx >> 6;
            sh[c * 65 + s * 32 + wi] =
                x[((size_t)(b * CC + c) * HH + h0 + s) * WW + w0 + wi];
        }
        __syncthreads();
        // ---- P: proj[64 pix][36]; 18 outputs/thread over 64 ch ----
        {
            float acc[18];
            for (int j = 0; j < 18; ++j) acc[j] = 0.f;
            for (int c = 0; c < CC; ++c) {
                float v = sh[c * 65 + pix];
                for (int j = 0; j < 18; ++j)
                    acc[j] = fmaf(xpw[(pg * 18 + j) * CC + c], v, acc[j]);
            }
            for (int j = 0; j < 18; ++j) pr[pix * 37 + pg * 18 + j] = acc[j];
        }
        // preload this thread's 32 u values before ytile aliases xt
        float uu[32];
        for (int wi = 0; wi < 32; ++wi) uu[wi] = sh[d * 65 + s_sc * 32 + wi];
        __syncthreads();
        // ---- S: 32 scan steps; y -> ytile (aliases xt, now dead) ----
        for (int wi = 0; wi < 32; ++wi) {
            const float* pp = &pr[(s_sc * 32 + wi) * 37];   // wave-uniform row
            float u = uu[wi];
            float draw = fmaf(pp[0], w40, fmaf(pp[1], w41,
                         fmaf(pp[2], w42, fmaf(pp[3], w43, bias))));
            float delta = softplus_f(draw);
            float du = delta * u;
            float y = 0.f;
            for (int n = 0; n < NN; ++n) {
                hs[n] = fmaf(__expf(delta * A[n]), hs[n], du * pp[4 + n]);
                y = fmaf(hs[n], pp[20 + n], y);
            }
            y = fmaf(u, Dd, y);
            sh[(s_sc * 64 + d) * 33 + wi] = y;  // bank (d+wi)%32: 2-way, free
        }
        __syncthreads();
        // ---- T: transposed float4 store, 128B per row ----
        for (int pass = 0; pass < 8; ++pass) {
            int r = pass * 16 + (t >> 3);   // s2*64 + d2, covers [0,128)
            int s2 = r >> 6, d2 = r & 63;
            int wq = (t & 7) * 4;
            const float* srcp = &sh[r * 33 + wq];
            *(float4*)&out[((size_t)(b * CC + d2) * HH + h0 + s2) * WW + w0 + wq] =
                make_float4(srcp[0], srcp[1], srcp[2], srcp[3]);
        }
        __syncthreads();
    }
}

// ---------------------------------------------------------------------------
// Vertical scan. grid=256, block=128. Block = 2 cols (b,w0/w0+1) x 64 ch.
// Lane order (d,s) = (t>>1, t&1): consecutive lane pairs share out lines.
// In-place f32 RMW of out (stream-ordered after k_h; same-thread RMW).
// ---------------------------------------------------------------------------
__global__ __launch_bounds__(128) void k_v(
    const float* __restrict__ x, const float* __restrict__ xpw,
    const float* __restrict__ A_log, const float* __restrict__ Dv,
    const float* __restrict__ dtw, const float* __restrict__ dtb,
    float* __restrict__ out)
{
    __shared__ float sh[64 * 65];  // xt[c][s*32+hi], live through scan
    __shared__ float pr[64 * 37];

    const int t = threadIdx.x;
    const int b = blockIdx.x >> 6;
    const int w0 = (blockIdx.x & 63) * 2;

    const int s_sc = t & 1;        // which column (w0 / w0+1)
    const int d = t >> 1;          // channel
    const int pix = t & 63;
    const int pg = t >> 6;

    float A[NN], hs[NN];
    for (int n = 0; n < NN; ++n) A[n] = -__expf(A_log[d * NN + n]);
    for (int n = 0; n < NN; ++n) hs[n] = 0.f;
    const float w40 = dtw[d * 4 + 0], w41 = dtw[d * 4 + 1];
    const float w42 = dtw[d * 4 + 2], w43 = dtw[d * 4 + 3];
    const float bias = dtb[d], Dd = Dv[d];

    for (int hh0 = 0; hh0 < HH; hh0 += 32) {
        // ---- L: stage xt[c][s*32+hi] (cols w0,w0+1) ----
        for (int pass = 0; pass < 32; ++pass) {
            int idx = pass * 128 + t;
            int hi = idx & 31, s = (idx >> 5) & 1, c = idx >> 6;
            sh[c * 65 + s * 32 + hi] =
                x[((size_t)(b * CC + c) * HH + hh0 + hi) * WW + w0 + s];
        }
        __syncthreads();
        // ---- P: proj ----
        {
            float acc[18];
            for (int j = 0; j < 18; ++j) acc[j] = 0.f;
            for (int c = 0; c < CC; ++c) {
                float v = sh[c * 65 + pix];
                for (int j = 0; j < 18; ++j)
                    acc[j] = fmaf(xpw[(pg * 18 + j) * CC + c], v, acc[j]);
            }
            for (int j = 0; j < 18; ++j) pr[pix * 37 + pg * 18 + j] = acc[j];
        }
        __syncthreads();
        // ---- S: 32 scan steps; u from live xt; f32 RMW out ----
        for (int hi = 0; hi < 32; ++hi) {
            const float* pp = &pr[(s_sc * 32 + hi) * 37];   // 2 rows/wave: free
            float u = sh[d * 65 + s_sc * 32 + hi];
            float draw = fmaf(pp[0], w40, fmaf(pp[1], w41,
                         fmaf(pp[2], w42, fmaf(pp[3], w43, bias))));
            float delta = softplus_f(draw);
            float du = delta * u;
            float y = 0.f;
            for (int n = 0; n < NN; ++n) {
                hs[n] = fmaf(__expf(delta * A[n]), hs[n], du * pp[4 + n]);
                y = fmaf(hs[n], pp[20 + n], y);
            }
            y = fmaf(u, Dd, y);
            size_t oaddr = ((size_t)(b * CC + d) * HH + hh0 + hi) * WW + w0 + s_sc;
            out[oaddr] = y + out[oaddr];   // same-thread RMW; lane pairs share lines
        }
        __syncthreads();
    }
}

// ---------------------------------------------------------------------------
extern "C" void kernel_launch(void* const* d_in, const int* in_sizes, int n_in,
                              void* d_out, int out_size, void* d_ws, size_t ws_size,
                              hipStream_t stream) {
    const float* x     = (const float*)d_in[0];  // f32 [4][64][128][128]
    const float* A_log = (const float*)d_in[1];  // f32 [64][16]
    const float* Dv    = (const float*)d_in[2];  // f32 [64]
    const float* xpw   = (const float*)d_in[3];  // f32 [36][64]
    const float* dtw   = (const float*)d_in[4];  // f32 [64][4]
    const float* dtb   = (const float*)d_in[5];  // f32 [64]
    float* out = (float*)d_out;                  // f32 [4][64][128][128]
    (void)d_ws; (void)ws_size;

    k_h<<<256, 128, 0, stream>>>(x, xpw, A_log, Dv, dtw, dtb, out);
    k_v<<<256, 128, 0, stream>>>(x, xpw, A_log, Dv, dtw, dtb, out);
}

// Round 11
// 212.807 us; speedup vs baseline: 1.2891x; 1.2891x over previous
//
#include <hip/hip_runtime.h>

#define BB 4
#define CC 64
#define HH 128
#define WW 128
#define NN 16
#define HW (HH*WW)
#define NPIX (BB*HW)

__device__ __forceinline__ float softplus_f(float x) {
    float e = __expf(-fabsf(x));
    return fmaxf(x, 0.0f) + __logf(1.0f + e);
}

// ===========================================================================
// K0: transpose x[b,c,h,w] -> xT[b,c,w,h].  grid 4096, block 256.
// ===========================================================================
__global__ __launch_bounds__(256) void k_tr(const float* __restrict__ x,
                                            float* __restrict__ xT)
{
    __shared__ float td[32 * 33];
    int t = threadIdx.x;
    int bc = blockIdx.x >> 4;              // b*CC + c
    int tb = blockIdx.x & 15;
    int h0 = (tb & 3) * 32;
    int w0 = (tb >> 2) * 32;
    const float* src = x + (size_t)bc * HW;
    float* dst = xT + (size_t)bc * HW;
    int r = t >> 3, q = t & 7;
    float4 v = *(const float4*)&src[(h0 + r) * WW + w0 + q * 4];   // coalesced
    td[r * 33 + q * 4 + 0] = v.x;
    td[r * 33 + q * 4 + 1] = v.y;
    td[r * 33 + q * 4 + 2] = v.z;
    td[r * 33 + q * 4 + 3] = v.w;
    __syncthreads();
    float4 o;                               // xT[w][h] = x[h][w] = td[h-h0][w-w0]
    o.x = td[(q * 4 + 0) * 33 + r];
    o.y = td[(q * 4 + 1) * 33 + r];
    o.z = td[(q * 4 + 2) * 33 + r];
    o.w = td[(q * 4 + 3) * 33 + r];
    *(float4*)&dst[(w0 + r) * HH + h0 + q * 4] = o;                // coalesced
}

// ===========================================================================
// K1: proj[pix][36] = sum_c x[b,c,hw] * xpw[p][c].  grid 256, block 256.
// ===========================================================================
__global__ __launch_bounds__(256) void k_proj(const float* __restrict__ x,
                                              const float* __restrict__ xpw,
                                              float* __restrict__ proj)
{
    __shared__ float wl[36 * 64];          // xpw copy, [p][c]
    int t = threadIdx.x;
    for (int i = t; i < 36 * 64; i += 256) wl[i] = xpw[i];
    __syncthreads();

    int pix = blockIdx.x * 256 + t;
    int b = pix >> 14;                     // / HW
    int hw = pix & (HW - 1);
    const float* xp = x + (size_t)b * CC * HW + hw;

    float acc[36];
#pragma unroll
    for (int p = 0; p < 36; ++p) acc[p] = 0.f;
    for (int c = 0; c < CC; ++c) {
        float v = xp[(size_t)c * HW];      // coalesced across lanes
#pragma unroll
        for (int p = 0; p < 36; ++p) acc[p] = fmaf(wl[p * 64 + c], v, acc[p]);
    }
    float* pp = proj + (size_t)pix * 36;   // 144B contiguous per lane
#pragma unroll
    for (int q = 0; q < 9; ++q)
        *(float4*)&pp[q * 4] = make_float4(acc[q*4], acc[q*4+1], acc[q*4+2], acc[q*4+3]);
}

// ===========================================================================
// K2: h-scan. grid 512 (= b*128 + h), block 512 = 64 d x 8 ng (2 states/lane).
// 16 waves/CU. Writes y_h directly to out (coalesced rows).
// ===========================================================================
__global__ __launch_bounds__(512) void k_hs(
    const float* __restrict__ x, const float* __restrict__ proj,
    const float* __restrict__ A_log, const float* __restrict__ Dv,
    const float* __restrict__ dtw, const float* __restrict__ dtb,
    float* __restrict__ out)
{
    __shared__ float xt[64 * 33];
    __shared__ float prc[32 * 37];
    __shared__ float yt[64 * 33];

    int t = threadIdx.x;
    int b = blockIdx.x >> 7;
    int h = blockIdx.x & 127;
    int d = t >> 3, ng = t & 7, n0 = ng * 2;

    float A0 = -__expf(A_log[d * NN + n0]);
    float A1 = -__expf(A_log[d * NN + n0 + 1]);
    float h0s = 0.f, h1s = 0.f;
    float w40 = dtw[d*4], w41 = dtw[d*4+1], w42 = dtw[d*4+2], w43 = dtw[d*4+3];
    float bias = dtb[d], Dd = Dv[d];
    int pixbase = (b * HH + h) * WW;

    for (int w0 = 0; w0 < WW; w0 += 32) {
        for (int i = t; i < 64 * 32; i += 512) {          // stage x rows
            int wi = i & 31, c = i >> 5;
            xt[c * 33 + wi] = x[((size_t)(b * CC + c) * HH + h) * WW + w0 + wi];
        }
        for (int i = t; i < 32 * 36; i += 512) {          // stage proj chunk
            int row = i / 36, e = i - row * 36;
            prc[row * 37 + e] = proj[(size_t)(pixbase + w0 + row) * 36 + e];
        }
        __syncthreads();
        for (int wi = 0; wi < 32; ++wi) {
            const float* pp = &prc[wi * 37];
            float u = xt[d * 33 + wi];                    // octet broadcast
            float draw = fmaf(pp[0], w40, fmaf(pp[1], w41,
                         fmaf(pp[2], w42, fmaf(pp[3], w43, bias))));
            float delta = softplus_f(draw);
            float du = delta * u;
            h0s = fmaf(__expf(delta * A0), h0s, du * pp[4 + n0]);
            h1s = fmaf(__expf(delta * A1), h1s, du * pp[4 + n0 + 1]);
            float y = fmaf(h0s, pp[20 + n0], h1s * pp[20 + n0 + 1]);
            y += __shfl_xor(y, 1);                        // octet butterfly
            y += __shfl_xor(y, 2);
            y += __shfl_xor(y, 4);
            if (ng == 0) yt[d * 33 + wi] = fmaf(u, Dd, y);
        }
        __syncthreads();
        {                                                 // coalesced out store
            int r = t >> 3, q = t & 7;                    // 64 x 8 = 512
            const float* sp = &yt[r * 33 + q * 4];
            *(float4*)&out[((size_t)(b * CC + r) * HH + h) * WW + w0 + q * 4] =
                make_float4(sp[0], sp[1], sp[2], sp[3]);
        }
        __syncthreads();
    }
}

// ===========================================================================
// K3: v-scan on xT. grid 512 (= b*128 + w), block 512. Writes yv[b,c,w,h].
// ===========================================================================
__global__ __launch_bounds__(512) void k_vs(
    const float* __restrict__ xT, const float* __restrict__ proj,
    const float* __restrict__ A_log, const float* __restrict__ Dv,
    const float* __restrict__ dtw, const float* __restrict__ dtb,
    float* __restrict__ yv)
{
    __shared__ float xt[64 * 33];
    __shared__ float prc[32 * 37];
    __shared__ float yt[64 * 33];

    int t = threadIdx.x;
    int b = blockIdx.x >> 7;
    int w = blockIdx.x & 127;
    int d = t >> 3, ng = t & 7, n0 = ng * 2;

    float A0 = -__expf(A_log[d * NN + n0]);
    float A1 = -__expf(A_log[d * NN + n0 + 1]);
    float h0s = 0.f, h1s = 0.f;
    float w40 = dtw[d*4], w41 = dtw[d*4+1], w42 = dtw[d*4+2], w43 = dtw[d*4+3];
    float bias = dtb[d], Dd = Dv[d];

    for (int hh0 = 0; hh0 < HH; hh0 += 32) {
        for (int i = t; i < 64 * 32; i += 512) {          // stage xT rows (coalesced)
            int hi = i & 31, c = i >> 5;
            xt[c * 33 + hi] = xT[((size_t)(b * CC + c) * WW + w) * HH + hh0 + hi];
        }
        for (int i = t; i < 32 * 36; i += 512) {          // stage proj (rows stride WW)
            int row = i / 36, e = i - row * 36;
            prc[row * 37 + e] =
                proj[(size_t)((b * HH + hh0 + row) * WW + w) * 36 + e];
        }
        __syncthreads();
        for (int hi = 0; hi < 32; ++hi) {
            const float* pp = &prc[hi * 37];
            float u = xt[d * 33 + hi];
            float draw = fmaf(pp[0], w40, fmaf(pp[1], w41,
                         fmaf(pp[2], w42, fmaf(pp[3], w43, bias))));
            float delta = softplus_f(draw);
            float du = delta * u;
            h0s = fmaf(__expf(delta * A0), h0s, du * pp[4 + n0]);
            h1s = fmaf(__expf(delta * A1), h1s, du * pp[4 + n0 + 1]);
            float y = fmaf(h0s, pp[20 + n0], h1s * pp[20 + n0 + 1]);
            y += __shfl_xor(y, 1);
            y += __shfl_xor(y, 2);
            y += __shfl_xor(y, 4);
            if (ng == 0) yt[d * 33 + hi] = fmaf(u, Dd, y);
        }
        __syncthreads();
        {                                                 // coalesced yv store
            int r = t >> 3, q = t & 7;
            const float* sp = &yt[r * 33 + q * 4];
            *(float4*)&yv[((size_t)(b * CC + r) * WW + w) * HH + hh0 + q * 4] =
                make_float4(sp[0], sp[1], sp[2], sp[3]);
        }
        __syncthreads();
    }
}

// ===========================================================================
// K4: out[b,c,h,w] += yv[b,c,w,h]  (32x32 transposed RMW). grid 4096, block 256.
// ===========================================================================
__global__ __launch_bounds__(256) void k_add(const float* __restrict__ yv,
                                             float* __restrict__ out)
{
    __shared__ float td[32 * 33];
    int t = threadIdx.x;
    int bc = blockIdx.x >> 4;
    int tb = blockIdx.x & 15;
    int w0 = (tb & 3) * 32;
    int h0 = (tb >> 2) * 32;
    const float* src = yv + (size_t)bc * HW;   // [w][h]
    float* dst = out + (size_t)bc * HW;        // [h][w]
    int r = t >> 3, q = t & 7;
    float4 v = *(const float4*)&src[(w0 + r) * HH + h0 + q * 4];   // coalesced
    td[r * 33 + q * 4 + 0] = v.x;
    td[r * 33 + q * 4 + 1] = v.y;
    td[r * 33 + q * 4 + 2] = v.z;
    td[r * 33 + q * 4 + 3] = v.w;
    __syncthreads();
    float* op = &dst[(h0 + r) * WW + w0 + q * 4];
    float4 o = *(float4*)op;                   // yv(w,h) = td[w-w0][h-h0]
    o.x += td[(q * 4 + 0) * 33 + r];
    o.y += td[(q * 4 + 1) * 33 + r];
    o.z += td[(q * 4 + 2) * 33 + r];
    o.w += td[(q * 4 + 3) * 33 + r];
    *(float4*)op = o;
}

// ===========================================================================
// Fallback (proven R10 kernels) if ws_size is too small.
// ===========================================================================
__global__ __launch_bounds__(128) void k_h_fb(
    const float* __restrict__ x, const float* __restrict__ xpw,
    const float* __restrict__ A_log, const float* __restrict__ Dv,
    const float* __restrict__ dtw, const float* __restrict__ dtb,
    float* __restrict__ out)
{
    __shared__ float sh[4224];
    __shared__ float pr[64 * 37];
    const int t = threadIdx.x;
    const int b = blockIdx.x >> 6;
    const int h0 = (blockIdx.x & 63) * 2;
    const int s_sc = t >> 6, d = t & 63, pix = t & 63, pg = t >> 6;
    float A[NN], hs[NN];
    for (int n = 0; n < NN; ++n) A[n] = -__expf(A_log[d * NN + n]);
    for (int n = 0; n < NN; ++n) hs[n] = 0.f;
    const float w40 = dtw[d*4], w41 = dtw[d*4+1], w42 = dtw[d*4+2], w43 = dtw[d*4+3];
    const float bias = dtb[d], Dd = Dv[d];
    for (int w0 = 0; w0 < WW; w0 += 32) {
        for (int pass = 0; pass < 32; ++pass) {
            int idx = pass * 128 + t;
            int wi = idx & 31, s = (idx >> 5) & 1, c = idx >> 6;
            sh[c * 65 + s * 32 + wi] = x[((size_t)(b*CC+c)*HH + h0+s)*WW + w0 + wi];
        }
        __syncthreads();
        {
            float acc[18];
            for (int j = 0; j < 18; ++j) acc[j] = 0.f;
            for (int c = 0; c < CC; ++c) {
                float v = sh[c * 65 + pix];
                for (int j = 0; j < 18; ++j)
                    acc[j] = fmaf(xpw[(pg*18+j)*CC + c], v, acc[j]);
            }
            for (int j = 0; j < 18; ++j) pr[pix*37 + pg*18 + j] = acc[j];
        }
        float uu[32];
        for (int wi = 0; wi < 32; ++wi) uu[wi] = sh[d*65 + s_sc*32 + wi];
        __syncthreads();
        for (int wi = 0; wi < 32; ++wi) {
            const float* pp = &pr[(s_sc*32 + wi)*37];
            float u = uu[wi];
            float draw = fmaf(pp[0],w40,fmaf(pp[1],w41,fmaf(pp[2],w42,fmaf(pp[3],w43,bias))));
            float delta = softplus_f(draw);
            float du = delta * u, y = 0.f;
            for (int n = 0; n < NN; ++n) {
                hs[n] = fmaf(__expf(delta*A[n]), hs[n], du*pp[4+n]);
                y = fmaf(hs[n], pp[20+n], y);
            }
            sh[(s_sc*64 + d)*33 + wi] = fmaf(u, Dd, y);
        }
        __syncthreads();
        for (int pass = 0; pass < 8; ++pass) {
            int r = pass*16 + (t >> 3);
            int s2 = r >> 6, d2 = r & 63, wq = (t & 7)*4;
            const float* sp = &sh[r*33 + wq];
            *(float4*)&out[((size_t)(b*CC+d2)*HH + h0+s2)*WW + w0 + wq] =
                make_float4(sp[0], sp[1], sp[2], sp[3]);
        }
        __syncthreads();
    }
}

__global__ __launch_bounds__(128) void k_v_fb(
    const float* __restrict__ x, const float* __restrict__ xpw,
    const float* __restrict__ A_log, const float* __restrict__ Dv,
    const float* __restrict__ dtw, const float* __restrict__ dtb,
    float* __restrict__ out)
{
    __shared__ float sh[64 * 65];
    __shared__ float pr[64 * 37];
    const int t = threadIdx.x;
    const int b = blockIdx.x >> 6;
    const int w0 = (blockIdx.x & 63) * 2;
    const int s_sc = t & 1, d = t >> 1, pix = t & 63, pg = t >> 6;
    float A[NN], hs[NN];
    for (int n = 0; n < NN; ++n) A[n] = -__expf(A_log[d * NN + n]);
    for (int n = 0; n < NN; ++n) hs[n] = 0.f;
    const float w40 = dtw[d*4], w41 = dtw[d*4+1], w42 = dtw[d*4+2], w43 = dtw[d*4+3];
    const float bias = dtb[d], Dd = Dv[d];
    for (int hh0 = 0; hh0 < HH; hh0 += 32) {
        for (int pass = 0; pass < 32; ++pass) {
            int idx = pass * 128 + t;
            int hi = idx & 31, s = (idx >> 5) & 1, c = idx >> 6;
            sh[c*65 + s*32 + hi] = x[((size_t)(b*CC+c)*HH + hh0+hi)*WW + w0 + s];
        }
        __syncthreads();
        {
            float acc[18];
            for (int j = 0; j < 18; ++j) acc[j] = 0.f;
            for (int c = 0; c < CC; ++c) {
                float v = sh[c*65 + pix];
                for (int j = 0; j < 18; ++j)
                    acc[j] = fmaf(xpw[(pg*18+j)*CC + c], v, acc[j]);
            }
            for (int j = 0; j < 18; ++j) pr[pix*37 + pg*18 + j] = acc[j];
        }
        __syncthreads();
        for (int hi = 0; hi < 32; ++hi) {
            const float* pp = &pr[(s_sc*32 + hi)*37];
            float u = sh[d*65 + s_sc*32 + hi];
            float draw = fmaf(pp[0],w40,fmaf(pp[1],w41,fmaf(pp[2],w42,fmaf(pp[3],w43,bias))));
            float delta = softplus_f(draw);
            float du = delta * u, y = 0.f;
            for (int n = 0; n < NN; ++n) {
                hs[n] = fmaf(__expf(delta*A[n]), hs[n], du*pp[4+n]);
                y = fmaf(hs[n], pp[20+n], y);
            }
            y = fmaf(u, Dd, y);
            size_t oaddr = ((size_t)(b*CC+d)*HH + hh0+hi)*WW + w0 + s_sc;
            out[oaddr] = y + out[oaddr];
        }
        __syncthreads();
    }
}

// ---------------------------------------------------------------------------
extern "C" void kernel_launch(void* const* d_in, const int* in_sizes, int n_in,
                              void* d_out, int out_size, void* d_ws, size_t ws_size,
                              hipStream_t stream) {
    const float* x     = (const float*)d_in[0];
    const float* A_log = (const float*)d_in[1];
    const float* Dv    = (const float*)d_in[2];
    const float* xpw   = (const float*)d_in[3];
    const float* dtw   = (const float*)d_in[4];
    const float* dtb   = (const float*)d_in[5];
    float* out = (float*)d_out;

    const size_t projN = (size_t)NPIX * 36;        // 9.44 MB
    const size_t planeN = (size_t)BB * CC * HW;    // 16.8 MB each
    const size_t need = (projN + 2 * planeN) * 4;  // 43 MB

    if (ws_size >= need) {
        float* proj = (float*)d_ws;
        float* xT   = proj + projN;
        float* yv   = xT + planeN;
        k_tr  <<<BB * CC * 16, 256, 0, stream>>>(x, xT);
        k_proj<<<NPIX / 256,   256, 0, stream>>>(x, xpw, proj);
        k_hs  <<<BB * HH,      512, 0, stream>>>(x,  proj, A_log, Dv, dtw, dtb, out);
        k_vs  <<<BB * WW,      512, 0, stream>>>(xT, proj, A_log, Dv, dtw, dtb, yv);
        k_add <<<BB * CC * 16, 256, 0, stream>>>(yv, out);
    } else {
        k_h_fb<<<256, 128, 0, stream>>>(x, xpw, A_log, Dv, dtw, dtb, out);
        k_v_fb<<<256, 128, 0, stream>>>(x, xpw, A_log, Dv, dtw, dtb, out);
    }
}

// Round 12
// 190.735 us; speedup vs baseline: 1.4383x; 1.1157x over previous
//
#include <hip/hip_runtime.h>

#define BB 4
#define CC 64
#define HH 128
#define WW 128
#define NN 16
#define HW (HH*WW)

__device__ __forceinline__ float softplus_f(float x) {
    float e = __expf(-fabsf(x));
    return fmaxf(x, 0.0f) + __logf(1.0f + e);
}

// ===========================================================================
// Fused proj+scan. grid 1024, block 512 = 64 d x 8 ng (2 SSM states/lane).
// Blocks [0,512): h-scan of row (b,h) -> out[b,c,h,:]   (coalesced)
// Blocks [512,1024): v-scan of col (b,w) -> yv[b,c,w,:] (coalesced, layout [b][c][w][h])
// One staged x-tile serves BOTH the 36-wide projection and the scan's u.
// Only 2 barriers per block; scan phase is barrier-free (read-only LDS).
// ===========================================================================
__global__ __launch_bounds__(512) void k_scan(
    const float* __restrict__ x, const float* __restrict__ xpw,
    const float* __restrict__ A_log, const float* __restrict__ Dv,
    const float* __restrict__ dtw, const float* __restrict__ dtb,
    float* __restrict__ out, float* __restrict__ yv)
{
    __shared__ float xt[64 * 129];   // [c][j], j = running index (w or h)
    __shared__ float wl[36 * 65];    // xpw, row-padded (65: conflict-free)
    __shared__ float prc[128 * 37];  // proj[j][36], row-padded

    const int t = threadIdx.x;
    const int half = blockIdx.x >> 9;        // 0 = h-scan, 1 = v-scan
    const int r9 = blockIdx.x & 511;
    const int b = r9 >> 7;
    const int L = r9 & 127;                  // fixed h (half 0) or fixed w (half 1)

    // ---- stage weights + x tile ----
    for (int i = t; i < 36 * 64; i += 512) {
        int p = i >> 6, c = i & 63;
        wl[p * 65 + c] = xpw[i];
    }
    if (half == 0) {
        for (int i = t; i < 64 * 128; i += 512) {       // rows: coalesced
            int c = i >> 7, j = i & 127;
            xt[c * 129 + j] = x[((size_t)(b * CC + c) * HH + L) * WW + j];
        }
    } else {
        for (int i = t; i < 64 * 128; i += 512) {       // cols: L2/L3-served gather
            int c = i >> 7, j = i & 127;
            xt[c * 129 + j] = x[((size_t)(b * CC + c) * HH + j) * WW + L];
        }
    }
    __syncthreads();

    // ---- proj for all 128 pixels of this line: thread = (pix, 9-col group) ----
    {
        const int pix = t >> 2, pg = t & 3;
        float acc[9];
#pragma unroll
        for (int j = 0; j < 9; ++j) acc[j] = 0.f;
        for (int c = 0; c < CC; ++c) {
            float v = xt[c * 129 + pix];                 // 16 addr x4 bcast: free
#pragma unroll
            for (int j = 0; j < 9; ++j)
                acc[j] = fmaf(wl[(pg * 9 + j) * 65 + c], v, acc[j]);
        }
#pragma unroll
        for (int j = 0; j < 9; ++j) prc[pix * 37 + pg * 9 + j] = acc[j];
    }
    __syncthreads();

    // ---- scan: 128 steps, no barriers; y via register buffer + float4 store ----
    const int d = t >> 3, ng = t & 7, n0 = ng * 2;
    const float A0 = -__expf(A_log[d * NN + n0]);
    const float A1 = -__expf(A_log[d * NN + n0 + 1]);
    const float w40 = dtw[d*4], w41 = dtw[d*4+1], w42 = dtw[d*4+2], w43 = dtw[d*4+3];
    const float bias = dtb[d], Dd = Dv[d];
    float h0s = 0.f, h1s = 0.f;
    float4 ybuf = make_float4(0.f, 0.f, 0.f, 0.f);
    float* drow = (half == 0 ? out : yv) + ((size_t)(b * CC + d) * 128 + L) * 128;

    for (int j0 = 0; j0 < 128; j0 += 4) {
        const bool cap = (((j0 >> 2) & 7) == ng);        // this lane owns j0..j0+3
#pragma unroll
        for (int k = 0; k < 4; ++k) {
            const int j = j0 + k;
            const float* pp = &prc[j * 37];              // wave-uniform row
            float u = xt[d * 129 + j];                   // 8 banks, free
            float draw = fmaf(pp[0], w40, fmaf(pp[1], w41,
                         fmaf(pp[2], w42, fmaf(pp[3], w43, bias))));
            float delta = softplus_f(draw);
            float du = delta * u;
            h0s = fmaf(__expf(delta * A0), h0s, du * pp[4 + n0]);
            h1s = fmaf(__expf(delta * A1), h1s, du * pp[5 + n0]);
            float y = fmaf(h0s, pp[20 + n0], h1s * pp[21 + n0]);
            y += __shfl_xor(y, 1);                       // octet reduction
            y += __shfl_xor(y, 2);
            y += __shfl_xor(y, 4);
            y = fmaf(u, Dd, y);
            if (cap) (&ybuf.x)[k] = y;
        }
        if ((j0 & 31) == 28)                             // end of 32-chunk
            *(float4*)&drow[(j0 & ~31) + ng * 4] = ybuf; // 8x128B segs/wave
    }
}

// ===========================================================================
// out[b,c,h,w] += yv[b,c,w,h]  (32x32 LDS-tile transposed RMW). R11-proven.
// ===========================================================================
__global__ __launch_bounds__(256) void k_add(const float* __restrict__ yv,
                                             float* __restrict__ out)
{
    __shared__ float td[32 * 33];
    int t = threadIdx.x;
    int bc = blockIdx.x >> 4;
    int tb = blockIdx.x & 15;
    int w0 = (tb & 3) * 32;
    int h0 = (tb >> 2) * 32;
    const float* src = yv + (size_t)bc * HW;   // [w][h]
    float* dst = out + (size_t)bc * HW;        // [h][w]
    int r = t >> 3, q = t & 7;
    float4 v = *(const float4*)&src[(w0 + r) * HH + h0 + q * 4];   // coalesced
    td[r * 33 + q * 4 + 0] = v.x;
    td[r * 33 + q * 4 + 1] = v.y;
    td[r * 33 + q * 4 + 2] = v.z;
    td[r * 33 + q * 4 + 3] = v.w;
    __syncthreads();
    float* op = &dst[(h0 + r) * WW + w0 + q * 4];
    float4 o = *(float4*)op;
    o.x += td[(q * 4 + 0) * 33 + r];
    o.y += td[(q * 4 + 1) * 33 + r];
    o.z += td[(q * 4 + 2) * 33 + r];
    o.w += td[(q * 4 + 3) * 33 + r];
    *(float4*)op = o;
}

// ---------------------------------------------------------------------------
extern "C" void kernel_launch(void* const* d_in, const int* in_sizes, int n_in,
                              void* d_out, int out_size, void* d_ws, size_t ws_size,
                              hipStream_t stream) {
    const float* x     = (const float*)d_in[0];
    const float* A_log = (const float*)d_in[1];
    const float* Dv    = (const float*)d_in[2];
    const float* xpw   = (const float*)d_in[3];
    const float* dtw   = (const float*)d_in[4];
    const float* dtb   = (const float*)d_in[5];
    float* out = (float*)d_out;
    float* yv  = (float*)d_ws;       // 16.8 MB; ws >= 43 MB proven in R11

    k_scan<<<1024, 512, 0, stream>>>(x, xpw, A_log, Dv, dtw, dtb, out, yv);
    k_add <<<BB * CC * 16, 256, 0, stream>>>(yv, out);
}

// Round 13
// 156.045 us; speedup vs baseline: 1.7581x; 1.2223x over previous
//
#include <hip/hip_runtime.h>

#define BB 4
#define CC 64
#define HH 128
#define WW 128
#define NN 16
#define HW (HH*WW)

__device__ __forceinline__ float softplus_f(float x) {
    float e = __expf(-fabsf(x));
    return fmaxf(x, 0.0f) + __logf(1.0f + e);
}

// ===========================================================================
// Fused proj+scan. grid 1024, block 256 = 64 d x 4 ng (4 SSM states/lane).
// Blocks [0,512): h-scan of row (b,L=h) -> out[b,c,h,:]
// Blocks [512,1024): v-scan of col (b,L=w) -> yv[b,c,w,:]  ([b][c][w][h])
// Phases: stage x-line -> proj (xpw via wave-uniform global reads) ->
//         per 32-chunk { delta precompute (once per (d,j)) ; 32 scan steps }.
// DS ops/lane-step: u + delta + B(b128) + C(b128) + 2 shfl = 6  (was 12).
// ===========================================================================
__global__ __launch_bounds__(256) void k_scan(
    const float* __restrict__ x, const float* __restrict__ xpw,
    const float* __restrict__ A_log, const float* __restrict__ Dv,
    const float* __restrict__ dtw, const float* __restrict__ dtb,
    float* __restrict__ out, float* __restrict__ yv)
{
    __shared__ float xt[64 * 132];   // x line [c][j], stride 132 (16B-aligned rows)
    __shared__ float bc[128 * 36];   // proj slots 4..35 (B,C) [j][p]
    __shared__ float dtr[128 * 4];   // proj slots 0..3 (dt_raw) [j][4]
    __shared__ float dlt[32 * 64];   // delta chunk [j&31][d]

    const int t = threadIdx.x;
    const int half = blockIdx.x >> 9;
    const int r9 = blockIdx.x & 511;
    const int b = r9 >> 7;
    const int L = r9 & 127;

    // ---- stage x line ----
    if (half == 0) {
#pragma unroll
        for (int k = 0; k < 8; ++k) {           // rows: float4 coalesced
            int i = k * 256 + t;
            int c = i >> 5, jq = i & 31;
            *(float4*)&xt[c * 132 + jq * 4] =
                *(const float4*)&x[((size_t)(b * CC + c) * HH + L) * WW + jq * 4];
        }
    } else {
#pragma unroll
        for (int p = 0; p < 32; ++p) {          // cols: L2/L3-served gather
            int i = p * 256 + t;
            int c = i >> 7, j = i & 127;
            xt[c * 132 + j] = x[((size_t)(b * CC + c) * HH + j) * WW + L];
        }
    }
    __syncthreads();

    // ---- proj: wave = (pixhalf, pg2); xpw read wave-uniform (scalar path) ----
    {
        const int wv = t >> 6, lane = t & 63;
        const int pg2 = __builtin_amdgcn_readfirstlane(wv & 1);
        const int pix = (wv >> 1) * 64 + lane;
        const int p0 = pg2 * 18;
        float acc[18];
#pragma unroll
        for (int j = 0; j < 18; ++j) acc[j] = 0.f;
        for (int c4 = 0; c4 < 16; ++c4) {
            float xv0 = xt[(c4 * 4 + 0) * 132 + pix];
            float xv1 = xt[(c4 * 4 + 1) * 132 + pix];
            float xv2 = xt[(c4 * 4 + 2) * 132 + pix];
            float xv3 = xt[(c4 * 4 + 3) * 132 + pix];
#pragma unroll
            for (int j = 0; j < 18; ++j) {
                float4 wq = *(const float4*)&xpw[(p0 + j) * CC + c4 * 4]; // uniform
                acc[j] = fmaf(wq.x, xv0, fmaf(wq.y, xv1,
                         fmaf(wq.z, xv2, fmaf(wq.w, xv3, acc[j]))));
            }
        }
        if (pg2 == 0) {
            *(float4*)&dtr[pix * 4] = make_float4(acc[0], acc[1], acc[2], acc[3]);
            *(float4*)&bc[pix * 36 + 4]  = make_float4(acc[4], acc[5], acc[6], acc[7]);
            *(float4*)&bc[pix * 36 + 8]  = make_float4(acc[8], acc[9], acc[10], acc[11]);
            *(float4*)&bc[pix * 36 + 12] = make_float4(acc[12], acc[13], acc[14], acc[15]);
            *(float2*)&bc[pix * 36 + 16] = make_float2(acc[16], acc[17]);
        } else {
            *(float2*)&bc[pix * 36 + 18] = make_float2(acc[0], acc[1]);
            *(float4*)&bc[pix * 36 + 20] = make_float4(acc[2], acc[3], acc[4], acc[5]);
            *(float4*)&bc[pix * 36 + 24] = make_float4(acc[6], acc[7], acc[8], acc[9]);
            *(float4*)&bc[pix * 36 + 28] = make_float4(acc[10], acc[11], acc[12], acc[13]);
            *(float4*)&bc[pix * 36 + 32] = make_float4(acc[14], acc[15], acc[16], acc[17]);
        }
    }
    __syncthreads();

    // ---- scan setup ----
    const int d = t >> 2, ng = t & 3, n0 = ng * 4;
    float A0 = -__expf(A_log[d * NN + n0 + 0]);
    float A1 = -__expf(A_log[d * NN + n0 + 1]);
    float A2 = -__expf(A_log[d * NN + n0 + 2]);
    float A3 = -__expf(A_log[d * NN + n0 + 3]);
    const float Dd = Dv[d];
    float h0 = 0.f, h1 = 0.f, h2 = 0.f, h3 = 0.f;
    // delta-phase identity
    const int dd = t & 63, jb = t >> 6;
    const float4 wt4 = *(const float4*)&dtw[dd * 4];
    const float bdd = dtb[dd];
    float* drow = (half == 0 ? out : yv) + ((size_t)(b * CC + d) * 128 + L) * 128;

    for (int ch = 0; ch < 4; ++ch) {
        if (ch) __syncthreads();                 // prior chunk's dlt reads done
        // ---- delta precompute: once per (d,j) ----
#pragma unroll
        for (int k = 0; k < 8; ++k) {
            int jl = jb * 8 + k;
            float4 dr = *(const float4*)&dtr[(ch * 32 + jl) * 4];  // bcast row
            float draw = fmaf(dr.x, wt4.x, fmaf(dr.y, wt4.y,
                         fmaf(dr.z, wt4.z, fmaf(dr.w, wt4.w, bdd))));
            dlt[jl * 64 + dd] = softplus_f(draw);
        }
        __syncthreads();
        // ---- 32 scan steps, no barriers ----
        float yb[8];
        for (int jo = 0; jo < 4; ++jo) {
#pragma unroll
            for (int uu = 0; uu < 8; ++uu) {
                const int jl = jo * 8 + uu;
                const int j = ch * 32 + jl;
                float delta = dlt[jl * 64 + d];
                float u = xt[d * 132 + j];
                float4 Bv = *(const float4*)&bc[j * 36 + 4 + n0];
                float4 Cv = *(const float4*)&bc[j * 36 + 20 + n0];
                float du = delta * u;
                h0 = fmaf(__expf(delta * A0), h0, du * Bv.x);
                h1 = fmaf(__expf(delta * A1), h1, du * Bv.y);
                h2 = fmaf(__expf(delta * A2), h2, du * Bv.z);
                h3 = fmaf(__expf(delta * A3), h3, du * Bv.w);
                float y = fmaf(h0, Cv.x, fmaf(h1, Cv.y,
                          fmaf(h2, Cv.z, h3 * Cv.w)));
                y += __shfl_xor(y, 1);           // quad reduction
                y += __shfl_xor(y, 2);
                y = fmaf(u, Dd, y);
                if (ng == jo) yb[uu] = y;        // lane ng owns j-range [8ng,8ng+8)
            }
        }
        *(float4*)&drow[ch * 32 + ng * 8]     = make_float4(yb[0], yb[1], yb[2], yb[3]);
        *(float4*)&drow[ch * 32 + ng * 8 + 4] = make_float4(yb[4], yb[5], yb[6], yb[7]);
    }
}

// ===========================================================================
// out[b,c,h,w] += yv[b,c,w,h]  (32x32 LDS-tile transposed RMW). R11-proven.
// ===========================================================================
__global__ __launch_bounds__(256) void k_add(const float* __restrict__ yv,
                                             float* __restrict__ out)
{
    __shared__ float td[32 * 33];
    int t = threadIdx.x;
    int bc_ = blockIdx.x >> 4;
    int tb = blockIdx.x & 15;
    int w0 = (tb & 3) * 32;
    int h0 = (tb >> 2) * 32;
    const float* src = yv + (size_t)bc_ * HW;   // [w][h]
    float* dst = out + (size_t)bc_ * HW;        // [h][w]
    int r = t >> 3, q = t & 7;
    float4 v = *(const float4*)&src[(w0 + r) * HH + h0 + q * 4];
    td[r * 33 + q * 4 + 0] = v.x;
    td[r * 33 + q * 4 + 1] = v.y;
    td[r * 33 + q * 4 + 2] = v.z;
    td[r * 33 + q * 4 + 3] = v.w;
    __syncthreads();
    float* op = &dst[(h0 + r) * WW + w0 + q * 4];
    float4 o = *(float4*)op;
    o.x += td[(q * 4 + 0) * 33 + r];
    o.y += td[(q * 4 + 1) * 33 + r];
    o.z += td[(q * 4 + 2) * 33 + r];
    o.w += td[(q * 4 + 3) * 33 + r];
    *(float4*)op = o;
}

// ---------------------------------------------------------------------------
extern "C" void kernel_launch(void* const* d_in, const int* in_sizes, int n_in,
                              void* d_out, int out_size, void* d_ws, size_t ws_size,
                              hipStream_t stream) {
    const float* x     = (const float*)d_in[0];
    const float* A_log = (const float*)d_in[1];
    const float* Dv    = (const float*)d_in[2];
    const float* xpw   = (const float*)d_in[3];
    const float* dtw   = (const float*)d_in[4];
    const float* dtb   = (const float*)d_in[5];
    float* out = (float*)d_out;
    float* yv  = (float*)d_ws;       // 16.8 MB; ws >= 43 MB proven in R11

    k_scan<<<1024, 256, 0, stream>>>(x, xpw, A_log, Dv, dtw, dtb, out, yv);
    k_add <<<BB * CC * 16, 256, 0, stream>>>(yv, out);
}

// Round 14
// 150.473 us; speedup vs baseline: 1.8232x; 1.0370x over previous
//
#include <hip/hip_runtime.h>

#define BB 4
#define CC 64
#define HH 128
#define WW 128
#define NN 16
#define HW (HH*WW)

__device__ __forceinline__ float softplus_f(float x) {
    float e = __expf(-fabsf(x));
    return fmaxf(x, 0.0f) + __logf(1.0f + e);
}

// ===========================================================================
// Fused proj+scan. grid 1024, block 256 = 64 d x 4 ng (4 SSM states/lane).
// Blocks [0,512): h-scan of row (b,L=h) -> out[b,c,h,:]
// Blocks [512,1024): v-scan of col (b,L=w) -> yv[b,c,w,:]  ([b][c][w][h])
// LDS 52 KB -> 3 blocks/CU (12 waves).  xt XOR-swizzled, B/C group-swizzled.
// ===========================================================================
__global__ __launch_bounds__(256) void k_scan(
    const float* __restrict__ x, const float* __restrict__ xpw,
    const float* __restrict__ A_log, const float* __restrict__ Dv,
    const float* __restrict__ dtw, const float* __restrict__ dtb,
    float* __restrict__ out, float* __restrict__ yv)
{
    __shared__ float xt[128 * 64];   // 32 KB  x line, (j,c) at j*64+((c+j)&63)
    __shared__ float bcs[128 * 32];  // 16 KB  B/C, group g at j*32+((g^(j&7))<<2)
    __shared__ float dtr[128 * 4];   //  2 KB  dt_raw per pixel
    __shared__ float dlt[8 * 64];    //  2 KB  delta chunk [jl][d]

    const int t = threadIdx.x;
    const int half = blockIdx.x >> 9;
    const int r9 = blockIdx.x & 511;
    const int b = r9 >> 7;
    const int L = r9 & 127;

    // ---- stage x line into swizzled xt ----
    if (half == 0) {
#pragma unroll
        for (int k = 0; k < 8; ++k) {            // rows: float4 coalesced global
            int i = k * 256 + t;
            int c = i >> 5, jq = i & 31;
            float4 v = *(const float4*)&x[((size_t)(b * CC + c) * HH + L) * WW + jq * 4];
            int j0 = jq * 4;
            xt[(j0 + 0) * 64 + ((c + j0 + 0) & 63)] = v.x;
            xt[(j0 + 1) * 64 + ((c + j0 + 1) & 63)] = v.y;
            xt[(j0 + 2) * 64 + ((c + j0 + 2) & 63)] = v.z;
            xt[(j0 + 3) * 64 + ((c + j0 + 3) & 63)] = v.w;
        }
    } else {
#pragma unroll
        for (int p = 0; p < 32; ++p) {           // cols: L2/L3-served gather
            int c = t & 63, j = p * 4 + (t >> 6);
            xt[j * 64 + ((c + j) & 63)] =
                x[((size_t)(b * CC + c) * HH + j) * WW + L];
        }
    }
    __syncthreads();

    // ---- proj: wave pair covers (64 pix) x (18 of 36 cols); xpw uniform ----
    {
        const int wv = t >> 6, lane = t & 63;
        const int pg2 = __builtin_amdgcn_readfirstlane(wv & 1);
        const int pix = (wv >> 1) * 64 + lane;
        const int p0 = pg2 * 18;
        const int sw = pix & 7;
        float acc[18];
#pragma unroll
        for (int j = 0; j < 18; ++j) acc[j] = 0.f;
        for (int c4 = 0; c4 < 16; ++c4) {
            float xv0 = xt[pix * 64 + ((c4 * 4 + 0 + pix) & 63)];
            float xv1 = xt[pix * 64 + ((c4 * 4 + 1 + pix) & 63)];
            float xv2 = xt[pix * 64 + ((c4 * 4 + 2 + pix) & 63)];
            float xv3 = xt[pix * 64 + ((c4 * 4 + 3 + pix) & 63)];
#pragma unroll
            for (int j = 0; j < 18; ++j) {
                float4 wq = *(const float4*)&xpw[(p0 + j) * CC + c4 * 4];
                acc[j] = fmaf(wq.x, xv0, fmaf(wq.y, xv1,
                         fmaf(wq.z, xv2, fmaf(wq.w, xv3, acc[j]))));
            }
        }
        float* bp = &bcs[pix * 32];
        if (pg2 == 0) {
            *(float4*)&dtr[pix * 4] = make_float4(acc[0], acc[1], acc[2], acc[3]);
            // B groups 0..2 full; group 3 split (B12,B13 here)
            *(float4*)&bp[((0 ^ sw) << 2)] = make_float4(acc[4], acc[5], acc[6], acc[7]);
            *(float4*)&bp[((1 ^ sw) << 2)] = make_float4(acc[8], acc[9], acc[10], acc[11]);
            *(float4*)&bp[((2 ^ sw) << 2)] = make_float4(acc[12], acc[13], acc[14], acc[15]);
            bp[((3 ^ sw) << 2) + 0] = acc[16];
            bp[((3 ^ sw) << 2) + 1] = acc[17];
        } else {
            // B14,B15 finish group 3; C groups 4..7 full
            bp[((3 ^ sw) << 2) + 2] = acc[0];
            bp[((3 ^ sw) << 2) + 3] = acc[1];
            *(float4*)&bp[((4 ^ sw) << 2)] = make_float4(acc[2], acc[3], acc[4], acc[5]);
            *(float4*)&bp[((5 ^ sw) << 2)] = make_float4(acc[6], acc[7], acc[8], acc[9]);
            *(float4*)&bp[((6 ^ sw) << 2)] = make_float4(acc[10], acc[11], acc[12], acc[13]);
            *(float4*)&bp[((7 ^ sw) << 2)] = make_float4(acc[14], acc[15], acc[16], acc[17]);
        }
    }

    // ---- scan setup ----
    const int d = t >> 2, ng = t & 3, n0 = ng * 4;
    float A0 = -__expf(A_log[d * NN + n0 + 0]);
    float A1 = -__expf(A_log[d * NN + n0 + 1]);
    float A2 = -__expf(A_log[d * NN + n0 + 2]);
    float A3 = -__expf(A_log[d * NN + n0 + 3]);
    const float Dd = Dv[d];
    float h0 = 0.f, h1 = 0.f, h2 = 0.f, h3 = 0.f;
    // delta-phase identity: 64 d x (2 j per thread)
    const int dd = t & 63, jb = t >> 6;
    const float4 wt4 = *(const float4*)&dtw[dd * 4];
    const float bdd = dtb[dd];
    float* drow = (half == 0 ? out : yv) + ((size_t)(b * CC + d) * 128 + L) * 128;

    for (int ch = 0; ch < 16; ++ch) {
        __syncthreads();                         // prev chunk's dlt reads done / proj done
        // ---- delta precompute: once per (d,j), 2 j per thread ----
#pragma unroll
        for (int k = 0; k < 2; ++k) {
            int jl = jb * 2 + k;
            float4 dr = *(const float4*)&dtr[(ch * 8 + jl) * 4];   // bcast
            float draw = fmaf(dr.x, wt4.x, fmaf(dr.y, wt4.y,
                         fmaf(dr.z, wt4.z, fmaf(dr.w, wt4.w, bdd))));
            dlt[jl * 64 + dd] = softplus_f(draw);
        }
        __syncthreads();
        // ---- 8 scan steps, no barriers ----
        float y0 = 0.f, y1 = 0.f;
#pragma unroll
        for (int jl = 0; jl < 8; ++jl) {
            const int j = ch * 8 + jl;
            float delta = dlt[jl * 64 + d];
            float u = xt[j * 64 + ((d + j) & 63)];
            const int s = j & 7;
            float4 Bv = *(const float4*)&bcs[j * 32 + ((ng ^ s) << 2)];
            float4 Cv = *(const float4*)&bcs[j * 32 + (((4 + ng) ^ s) << 2)];
            float du = delta * u;
            h0 = fmaf(__expf(delta * A0), h0, du * Bv.x);
            h1 = fmaf(__expf(delta * A1), h1, du * Bv.y);
            h2 = fmaf(__expf(delta * A2), h2, du * Bv.z);
            h3 = fmaf(__expf(delta * A3), h3, du * Bv.w);
            float y = fmaf(h0, Cv.x, fmaf(h1, Cv.y, fmaf(h2, Cv.z, h3 * Cv.w)));
            y += __shfl_xor(y, 1);               // quad reduction
            y += __shfl_xor(y, 2);
            y = fmaf(u, Dd, y);
            if (ng == (jl >> 1)) { if (jl & 1) y1 = y; else y0 = y; }
        }
        *(float2*)&drow[ch * 8 + ng * 2] = make_float2(y0, y1);
    }
}

// ===========================================================================
// out[b,c,h,w] += yv[b,c,w,h]  (32x32 LDS-tile transposed RMW). R11-proven.
// ===========================================================================
__global__ __launch_bounds__(256) void k_add(const float* __restrict__ yv,
                                             float* __restrict__ out)
{
    __shared__ float td[32 * 33];
    int t = threadIdx.x;
    int bc_ = blockIdx.x >> 4;
    int tb = blockIdx.x & 15;
    int w0 = (tb & 3) * 32;
    int h0 = (tb >> 2) * 32;
    const float* src = yv + (size_t)bc_ * HW;   // [w][h]
    float* dst = out + (size_t)bc_ * HW;        // [h][w]
    int r = t >> 3, q = t & 7;
    float4 v = *(const float4*)&src[(w0 + r) * HH + h0 + q * 4];
    td[r * 33 + q * 4 + 0] = v.x;
    td[r * 33 + q * 4 + 1] = v.y;
    td[r * 33 + q * 4 + 2] = v.z;
    td[r * 33 + q * 4 + 3] = v.w;
    __syncthreads();
    float* op = &dst[(h0 + r) * WW + w0 + q * 4];
    float4 o = *(float4*)op;
    o.x += td[(q * 4 + 0) * 33 + r];
    o.y += td[(q * 4 + 1) * 33 + r];
    o.z += td[(q * 4 + 2) * 33 + r];
    o.w += td[(q * 4 + 3) * 33 + r];
    *(float4*)op = o;
}

// ---------------------------------------------------------------------------
extern "C" void kernel_launch(void* const* d_in, const int* in_sizes, int n_in,
                              void* d_out, int out_size, void* d_ws, size_t ws_size,
                              hipStream_t stream) {
    const float* x     = (const float*)d_in[0];
    const float* A_log = (const float*)d_in[1];
    const float* Dv    = (const float*)d_in[2];
    const float* xpw   = (const float*)d_in[3];
    const float* dtw   = (const float*)d_in[4];
    const float* dtb   = (const float*)d_in[5];
    float* out = (float*)d_out;
    float* yv  = (float*)d_ws;       // 16.8 MB; ws >= 43 MB proven in R11

    k_scan<<<1024, 256, 0, stream>>>(x, xpw, A_log, Dv, dtw, dtb, out, yv);
    k_add <<<BB * CC * 16, 256, 0, stream>>>(yv, out);
}